// Round 1
// baseline (371.854 us; speedup 1.0000x reference)
//
#include <hip/hip_runtime.h>
#include <hip/hip_bf16.h>

// Problem constants: B=4, N=1024, H=64, D=64, FE=16
#define NTOK   1024
#define NROWS  4096          // B*N
#define HD     64            // H == D == 64

// ---------------------------------------------------------------------------
// K1: z[row,d] = dot(h0[row,:], w_fc[d,:]);  sj[row]=z·a1, si[row]=z·a2
// grid = 4096 blocks, 64 threads (1 wave)
// ---------------------------------------------------------------------------
__global__ __launch_bounds__(64) void k1_fc(
    const float* __restrict__ h0, const float* __restrict__ w_fc,
    const float* __restrict__ w_attn,
    float* __restrict__ z, float* __restrict__ si, float* __restrict__ sj)
{
    const int row = blockIdx.x;
    const int d   = threadIdx.x;           // 0..63
    __shared__ float sh[HD];
    sh[d] = h0[row * HD + d];
    __syncthreads();

    float acc = 0.f;
    #pragma unroll
    for (int h = 0; h < HD; ++h)
        acc = fmaf(sh[h], w_fc[d * HD + h], acc);
    z[row * HD + d] = acc;

    float v1 = acc * w_attn[d];        // a1[d] -> sj
    float v2 = acc * w_attn[HD + d];   // a2[d] -> si
    #pragma unroll
    for (int off = 32; off; off >>= 1) {
        v1 += __shfl_down(v1, off);
        v2 += __shfl_down(v2, off);
    }
    if (d == 0) { sj[row] = v1; si[row] = v2; }
}

// ---------------------------------------------------------------------------
// K2: per (b,i) row: stream e[b,i,:,:] (64 KB), s_ij = lrelu(si_i + sj_j + e·a3),
//     online row softmax stats -> M[row], R[row].
// grid = 4096 blocks, 256 threads; thread t handles j = t, t+256, t+512, t+768
// ---------------------------------------------------------------------------
__global__ __launch_bounds__(256) void k2_row(
    const float* __restrict__ e, const float* __restrict__ w_attn,
    const float* __restrict__ si, const float* __restrict__ sj,
    float* __restrict__ Mrow, float* __restrict__ Rrow)
{
    const int row = blockIdx.x;            // b*N + i
    const int b   = row >> 10;
    const int tid = threadIdx.x;

    const float4* a3v = (const float4*)(w_attn + 2 * HD);
    const float4 a30 = a3v[0], a31 = a3v[1], a32 = a3v[2], a33 = a3v[3];

    const float  si_r = si[row];
    const float4* ev  = (const float4*)(e + (size_t)row * (NTOK * 16));
    const float* sjb  = sj + b * NTOK;

    float sv[4];
    #pragma unroll
    for (int it = 0; it < 4; ++it) {
        const int j = tid + it * 256;
        const float4* p = ev + (size_t)j * 4;   // 64 contiguous bytes / thread
        const float4 e0 = p[0], e1 = p[1], e2 = p[2], e3 = p[3];
        float se = e0.x*a30.x + e0.y*a30.y + e0.z*a30.z + e0.w*a30.w;
        se      += e1.x*a31.x + e1.y*a31.y + e1.z*a31.z + e1.w*a31.w;
        se      += e2.x*a32.x + e2.y*a32.y + e2.z*a32.z + e2.w*a32.w;
        se      += e3.x*a33.x + e3.y*a33.y + e3.z*a33.z + e3.w*a33.w;
        float s = si_r + sjb[j] + se;
        s = (s > 0.f) ? s : 0.01f * s;          // leaky_relu, slope 0.01
        sv[it] = s;
    }

    // per-thread max-then-sum (exact, 4 values)
    float m = fmaxf(fmaxf(sv[0], sv[1]), fmaxf(sv[2], sv[3]));
    float r = __expf(sv[0] - m) + __expf(sv[1] - m)
            + __expf(sv[2] - m) + __expf(sv[3] - m);

    // wave (m,r) butterfly over 64 lanes
    #pragma unroll
    for (int off = 1; off < 64; off <<= 1) {
        float om  = __shfl_xor(m, off);
        float orr = __shfl_xor(r, off);
        float nm  = fmaxf(m, om);
        r = r * __expf(m - nm) + orr * __expf(om - nm);
        m = nm;
    }

    // cross-wave (4 waves) via LDS
    __shared__ float sm[4], sr[4];
    if ((tid & 63) == 0) { sm[tid >> 6] = m; sr[tid >> 6] = r; }
    __syncthreads();
    if (tid == 0) {
        float M = sm[0], R = sr[0];
        #pragma unroll
        for (int w = 1; w < 4; ++w) {
            float om = sm[w], orr = sr[w];
            float nm = fmaxf(M, om);
            R = R * __expf(M - nm) + orr * __expf(om - nm);
            M = nm;
        }
        Mrow[row] = M; Rrow[row] = R;
    }
}

// ---------------------------------------------------------------------------
// K3: per batch b: m_b = max_i M_i ; Z_b = sum_i R_i * exp(M_i - m_b)
// grid = 4 blocks, 1024 threads (16 waves)
// ---------------------------------------------------------------------------
__global__ __launch_bounds__(1024) void k3_batch(
    const float* __restrict__ Mrow, const float* __restrict__ Rrow,
    float* __restrict__ mz)
{
    const int b = blockIdx.x;
    const int i = threadIdx.x;             // 0..1023
    const float Mi = Mrow[b * NTOK + i];
    const float Ri = Rrow[b * NTOK + i];

    __shared__ float red[16];
    __shared__ float bc;

    float m = Mi;
    #pragma unroll
    for (int off = 32; off; off >>= 1) m = fmaxf(m, __shfl_xor(m, off));
    if ((i & 63) == 0) red[i >> 6] = m;
    __syncthreads();
    if (i == 0) {
        float mm = red[0];
        #pragma unroll
        for (int w = 1; w < 16; ++w) mm = fmaxf(mm, red[w]);
        bc = mm;
    }
    __syncthreads();
    const float mb = bc;

    float ssum = Ri * __expf(Mi - mb);
    #pragma unroll
    for (int off = 32; off; off >>= 1) ssum += __shfl_xor(ssum, off);
    __syncthreads();
    if ((i & 63) == 0) red[i >> 6] = ssum;
    __syncthreads();
    if (i == 0) {
        float Z = 0.f;
        #pragma unroll
        for (int w = 0; w < 16; ++w) Z += red[w];
        mz[b * 2]     = mb;
        mz[b * 2 + 1] = Z;
    }
}

// ---------------------------------------------------------------------------
// K4: out[row,:] = (R[row]*exp(M[row]-m_b)/Z_b) * z[row,:]   (float4)
// grid = 256 blocks, 256 threads -> 64K float4
// ---------------------------------------------------------------------------
__global__ __launch_bounds__(256) void k4_out(
    const float* __restrict__ z, const float* __restrict__ Mrow,
    const float* __restrict__ Rrow, const float* __restrict__ mz,
    float* __restrict__ out)
{
    const int idx = blockIdx.x * 256 + threadIdx.x;  // float4 index
    const int row = idx >> 4;                        // 16 float4 per row
    const int b   = row >> 10;
    const float scale = Rrow[row] * __expf(Mrow[row] - mz[b * 2]) / mz[b * 2 + 1];
    const float4 zv = ((const float4*)z)[idx];
    float4 o;
    o.x = zv.x * scale; o.y = zv.y * scale;
    o.z = zv.z * scale; o.w = zv.w * scale;
    ((float4*)out)[idx] = o;
}

// ---------------------------------------------------------------------------
extern "C" void kernel_launch(void* const* d_in, const int* in_sizes, int n_in,
                              void* d_out, int out_size, void* d_ws, size_t ws_size,
                              hipStream_t stream)
{
    const float* h0     = (const float*)d_in[0];   // (4,1024,64)
    const float* e      = (const float*)d_in[1];   // (4,1024,1024,16)
    const float* w_fc   = (const float*)d_in[2];   // (64,64)
    const float* w_attn = (const float*)d_in[3];   // (144,)
    float* out = (float*)d_out;                    // (4,1024,64) fp32

    // workspace carve-up (floats)
    float* ws   = (float*)d_ws;
    float* z    = ws;                      // 4096*64 = 262144
    float* si   = z  + NROWS * HD;         // 4096
    float* sj   = si + NROWS;              // 4096
    float* Mrow = sj + NROWS;              // 4096
    float* Rrow = Mrow + NROWS;            // 4096
    float* mz   = Rrow + NROWS;            // 8

    k1_fc   <<<NROWS, 64,   0, stream>>>(h0, w_fc, w_attn, z, si, sj);
    k2_row  <<<NROWS, 256,  0, stream>>>(e, w_attn, si, sj, Mrow, Rrow);
    k3_batch<<<4,     1024, 0, stream>>>(Mrow, Rrow, mz);
    k4_out  <<<256,   256,  0, stream>>>(z, Mrow, Rrow, mz, out);
}